// Round 4
// baseline (1908.294 us; speedup 1.0000x reference)
//
#include <hip/hip_runtime.h>
#include <cstdint>
#include <cstddef>

// ---------------------------------------------------------------------------
// OrderedMemoryDecoder (DEPTH=14, B=8, H=1024, V=32000) for gfx950.
// R5: persistent tree kernel — all 13 levels in ONE launch with device-scope
// grid barriers (blocks 0-127); W_out transpose overlapped on blocks 128-255.
// Tree cell GEMM is direct-to-register MFMA (no LDS, no block barriers).
// k_gemm/k_lse/k_norm_bf unchanged from R4.
// ---------------------------------------------------------------------------

typedef __attribute__((ext_vector_type(4))) float   f4;
typedef __attribute__((ext_vector_type(4))) float   f32x4;
typedef __attribute__((ext_vector_type(8))) __bf16  bf16x8;
typedef __attribute__((ext_vector_type(4))) unsigned short us4;
typedef __attribute__((ext_vector_type(8))) unsigned short us8;

constexpr int DEPTH = 14;
constexpr int Bb = 8;
constexpr int Hd = 1024;
constexpr int Vv = 32000;
constexpr int NT = Vv / 128;   // 250 N-tiles in big GEMM
constexpr int MAXT = 512;
constexpr int MAXS = 4096;
constexpr int MAXP = 32;
constexpr float L2E = 1.44269504088896340736f;

struct SB {
  int lvlOff[DEPTH + 1];
  int lvlK[DEPTH];
  int len[MAXT];
  int lch[MAXT], rch[MAXT];
  int parCnt[DEPTH];
  int parRows[DEPTH][MAXP];
  int T;
  int nS;
  int sOut[MAXS], sIn[MAXS];
  int nStart, nEnd;
  int startIdx[16], endIdx[16];
};

constexpr int ceil75(int L) {
  constexpr int t[14] = {0, 1, 2, 3, 3, 4, 4, 5, 5, 6, 6, 7, 7, 7};
  return t[L];
}

constexpr SB build() {
  SB s{};
  for (int i = 0; i < MAXT; i++) { s.lch[i] = -1; s.rch[i] = -1; }
  s.lvlOff[0] = 0; s.lvlK[0] = 1; s.len[0] = DEPTH;
  for (int l = 0; l < DEPTH - 1; l++) {
    int off = s.lvlOff[l], K = s.lvlK[l];
    int nxt = off + K, cnt = 0;
    for (int i = 0; i < K; i++) {
      int g = off + i;
      if (s.len[g] > 1) {
        int gl = nxt + 2 * cnt, gr = gl + 1;
        s.lch[g] = gl; s.rch[g] = gr;
        s.len[gl] = ceil75(s.len[g] - 1);
        s.len[gr] = s.len[g] - 1;
        s.parRows[l][cnt] = g;
        cnt++;
      }
    }
    s.parCnt[l] = cnt;
    s.lvlOff[l + 1] = nxt;
    s.lvlK[l + 1] = 2 * cnt;
  }
  s.T = s.lvlOff[DEPTH - 1] + s.lvlK[DEPTH - 1];
  s.nS = 0;
  for (int l = DEPTH - 2; l >= 0; l--) {
    for (int pi = 0; pi < s.parCnt[l]; pi++) {
      int g = s.parRows[l][pi];
      for (int u = s.lch[g]; u != -1; u = s.rch[u])
        for (int v = s.rch[g]; v != -1; v = s.lch[v]) {
          s.sOut[s.nS] = u; s.sIn[s.nS] = v; s.nS++;
        }
    }
  }
  s.nStart = 0;
  for (int u = 0; u != -1; u = s.lch[u]) s.startIdx[s.nStart++] = u;
  s.nEnd = 0;
  for (int u = 0; u != -1; u = s.rch[u]) s.endIdx[s.nEnd++] = u;
  return s;
}

constexpr SB HS = build();
__device__ const SB DS = build();

__device__ __forceinline__ unsigned short f2bf(float f) {
  union { float f; unsigned u; } v; v.f = f;
  unsigned r = v.u + 0x7fffu + ((v.u >> 16) & 1u);  // RNE
  return (unsigned short)(r >> 16);
}

// ----------------- device-scope grid barrier (tree-role blocks) -------------
__device__ __forceinline__ void gbar(int* bar, int nblk) {
  __syncthreads();
  __threadfence();                       // release our data writes (wbL2)
  if (threadIdx.x == 0) {
    int g = __hip_atomic_load(&bar[1], __ATOMIC_ACQUIRE, __HIP_MEMORY_SCOPE_AGENT);
    int a = __hip_atomic_fetch_add(&bar[0], 1, __ATOMIC_ACQ_REL,
                                   __HIP_MEMORY_SCOPE_AGENT);
    if (a == nblk - 1) {
      __hip_atomic_store(&bar[0], 0, __ATOMIC_RELAXED, __HIP_MEMORY_SCOPE_AGENT);
      __hip_atomic_fetch_add(&bar[1], 1, __ATOMIC_ACQ_REL,
                             __HIP_MEMORY_SCOPE_AGENT);
    } else {
      while (__hip_atomic_load(&bar[1], __ATOMIC_ACQUIRE,
                               __HIP_MEMORY_SCOPE_AGENT) == g) {
        __builtin_amdgcn_s_sleep(8);
      }
    }
  }
  __syncthreads();                       // all threads wait; acquire inv done
}

// --------------- W_cell[:1024,:] -> bf16, transposed [2048][1024] -----------
__global__ void k_wct(const float* __restrict__ Wc,
                      unsigned short* __restrict__ Wct) {
  __shared__ float t[32][33];
  int tx = threadIdx.x, ty = threadIdx.y;
  int n0 = blockIdx.x * 32, k0 = blockIdx.y * 32;
  for (int i = 0; i < 4; i++)
    t[ty + 8 * i][tx] = Wc[(size_t)(k0 + ty + 8 * i) * 2048 + n0 + tx];
  __syncthreads();
  for (int i = 0; i < 4; i++)
    Wct[(size_t)(n0 + ty + 8 * i) * Hd + k0 + tx] = f2bf(t[tx][ty + 8 * i]);
}

// ------------------------------ g and h0 ------------------------------------
__global__ void k_init(const float* __restrict__ x, const float* __restrict__ Wg,
                       const float* __restrict__ bg, const float* __restrict__ Win,
                       const float* __restrict__ bin, float* __restrict__ gbuf,
                       float* __restrict__ hidd, unsigned short* __restrict__ hiddb) {
  __shared__ float xs[Bb * Hd];
  __shared__ float part[Bb][128];
  int tid = threadIdx.x;
  int mat = blockIdx.y;
  const float* W = mat ? Win : Wg;
  const float* bias = mat ? bin : bg;
  for (int i = tid; i < Bb * Hd; i += 256) xs[i] = x[i];
  __syncthreads();
  int c = tid & 127, kh = tid >> 7;
  int col = blockIdx.x * 128 + c;
  float acc[Bb];
#pragma unroll
  for (int b = 0; b < Bb; b++) acc[b] = 0.f;
  for (int k = kh * 512; k < kh * 512 + 512; k++) {
    float w = W[(size_t)k * Hd + col];
#pragma unroll
    for (int b = 0; b < Bb; b++) acc[b] += xs[b * Hd + k] * w;
  }
  if (kh == 1)
    for (int b = 0; b < Bb; b++) part[b][c] = acc[b];
  __syncthreads();
  if (kh == 0) {
    for (int b = 0; b < Bb; b++) {
      float v = acc[b] + part[b][c] + bias[col];
      if (mat == 0) gbuf[b * Hd + col] = v;
      else { hidd[(size_t)b * Hd + col] = v; hiddb[(size_t)b * Hd + col] = f2bf(v); }
    }
  }
}

// --------------------- gW = g @ W_cell[1024:,:] + b_cell --------------------
__global__ void k_gw(const float* __restrict__ gbuf, const float* __restrict__ Wc,
                     const float* __restrict__ bc, float* __restrict__ gW) {
  __shared__ float xs[Bb * Hd];
  __shared__ float part[Bb][128];
  int tid = threadIdx.x;
  for (int i = tid; i < Bb * Hd; i += 256) xs[i] = gbuf[i];
  __syncthreads();
  int c = tid & 127, kh = tid >> 7;
  int col = blockIdx.x * 128 + c;
  float acc[Bb];
#pragma unroll
  for (int b = 0; b < Bb; b++) acc[b] = 0.f;
  for (int k = kh * 512; k < kh * 512 + 512; k++) {
    float w = Wc[(size_t)(Hd + k) * 2048 + col];
#pragma unroll
    for (int b = 0; b < Bb; b++) acc[b] += xs[b * Hd + k] * w;
  }
  if (kh == 1)
    for (int b = 0; b < Bb; b++) part[b][c] = acc[b];
  __syncthreads();
  if (kh == 0)
    for (int b = 0; b < Bb; b++)
      gW[(size_t)b * 2048 + col] = acc[b] + part[b][c] + bc[col];
}

// ---------------------- level-0 leaf log-softmax ----------------------------
__global__ void k_leaf0(const float* __restrict__ hidd, const float* __restrict__ Wl,
                        const float* __restrict__ bl, float* __restrict__ leaves) {
  int b = threadIdx.x >> 6, lane = threadIdx.x & 63;
  float d0 = 0.f, d1 = 0.f;
  for (int k = lane; k < Hd; k += 64) {
    float h = hidd[(size_t)b * Hd + k];
    d0 += h * Wl[2 * k];
    d1 += h * Wl[2 * k + 1];
  }
  for (int off = 32; off; off >>= 1) {
    d0 += __shfl_down(d0, off);
    d1 += __shfl_down(d1, off);
  }
  if (lane == 0) {
    float l0 = d0 + bl[0], l1 = d1 + bl[1];
    float m = fmaxf(l0, l1);
    float L = logf(expf(l0 - m) + expf(l1 - m));
    leaves[b * 2 + 0] = l0 - m - L;
    leaves[b * 2 + 1] = l1 - m - L;
  }
}

// -------------------- persistent tree + W_out transpose ---------------------
// blocks 0..127: all DEPTH-1 levels with grid barriers between phases.
//   phase A: per-wave 16-col strip GEMM (direct-to-reg MFMA, full K=1024),
//            z += gW, write zbuf + per-strip LN partial sums (deterministic).
//   phase B: per-wave (child, b): reduce 64 partials, LN+tanh, bf16 h write,
//            leaf log-softmax.
// blocks 128..255: W_out -> bf16 transposed (grid-stride over 128x64 tiles).
__global__ __launch_bounds__(256) void k_tree(
    unsigned short* __restrict__ hiddb, const unsigned short* __restrict__ Wct,
    const float* __restrict__ gW, const float* __restrict__ lng,
    const float* __restrict__ lnb, const float* __restrict__ Wl,
    const float* __restrict__ bl, float* __restrict__ leaves,
    float* __restrict__ zbuf, float* __restrict__ pstat, int* __restrict__ bar,
    const float* __restrict__ Wout, unsigned short* __restrict__ Wt) {
  __shared__ float tsh[64][129];
  int tid = threadIdx.x;
  if (blockIdx.x >= 128) {
    // ------------------------- W_out transpose role -------------------------
    for (int tile = blockIdx.x - 128; tile < 250 * 16; tile += 128) {
      int n0 = (tile % 250) * 128, k0 = (tile / 250) * 64;
#pragma unroll
      for (int i = 0; i < 8; i++) {
        int k = (tid >> 5) + 8 * i;
        int c = (tid & 31) * 4;
        f4 v = *(const f4*)&Wout[(size_t)(k0 + k) * Vv + n0 + c];
        tsh[k][c] = v.x; tsh[k][c + 1] = v.y;
        tsh[k][c + 2] = v.z; tsh[k][c + 3] = v.w;
      }
      __syncthreads();
#pragma unroll
      for (int pass = 0; pass < 4; pass++) {
        int n = (tid >> 3) + 32 * pass;
        int ks = (tid & 7) * 8;
        us8 o;
#pragma unroll
        for (int q2 = 0; q2 < 8; q2++) o[q2] = f2bf(tsh[ks + q2][n]);
        *(us8*)&Wt[(size_t)(n0 + n) * Hd + k0 + ks] = o;
      }
      __syncthreads();
    }
    return;
  }
  // ------------------------------ tree role ---------------------------------
  int w = tid >> 6, lane = tid & 63;
  int tw = blockIdx.x * 4 + w;          // 0..511
  int quad = lane >> 4, l15 = lane & 15;
  for (int l = 1; l < DEPTH; l++) {
    int Pc = DS.parCnt[l - 1];
    int off = DS.lvlOff[l];
    // ---- phase A: strip GEMM ----
    int nStrips = Pc * 128;
    for (int sidx = tw; sidx < nStrips; sidx += 512) {
      int p = sidx >> 7, cb = sidx & 127;
      int n0 = cb * 16;                 // col in [0,2048)
      int prow = DS.parRows[l - 1][p];
      const unsigned short* Arow = hiddb + ((size_t)prow * Bb + l15) * Hd;
      const unsigned short* Brow = Wct + (size_t)(n0 + l15) * Hd;
      f32x4 acc = {0.f, 0.f, 0.f, 0.f};
#pragma unroll 8
      for (int kk = 0; kk < 32; kk++) {
        bf16x8 a = *(const bf16x8*)(Arow + kk * 32 + quad * 8);
        bf16x8 bb = *(const bf16x8*)(Brow + kk * 32 + quad * 8);
        acc = __builtin_amdgcn_mfma_f32_16x16x32_bf16(a, bb, acc, 0, 0, 0);
      }
      // rows = quad*4+rr (valid <8), col = l15 [m89 C/D layout]
      int gcol = n0 + l15;
      float zv[4];
#pragma unroll
      for (int rr = 0; rr < 4; rr++) {
        int row = quad * 4 + rr;
        float zz = 0.f;
        if (row < 8) {
          zz = acc[rr] + gW[(size_t)row * 2048 + gcol];
          zbuf[((size_t)(p * Bb + row)) * 2048 + gcol] = zz;
        }
        zv[rr] = zz;
      }
      float s1v[4], s2v[4];
#pragma unroll
      for (int rr = 0; rr < 4; rr++) { s1v[rr] = zv[rr]; s2v[rr] = zv[rr] * zv[rr]; }
#pragma unroll
      for (int d = 1; d < 16; d <<= 1) {
#pragma unroll
        for (int rr = 0; rr < 4; rr++) {
          s1v[rr] += __shfl_xor(s1v[rr], d);
          s2v[rr] += __shfl_xor(s2v[rr], d);
        }
      }
      if (l15 == 0 && quad < 2) {
#pragma unroll
        for (int rr = 0; rr < 4; rr++) {
          int row = quad * 4 + rr;
          size_t si = (((size_t)p * 128 + cb) * 8 + row) * 2;
          pstat[si] = s1v[rr];
          pstat[si + 1] = s2v[rr];
        }
      }
    }
    gbar(bar, 128);
    // ---- phase B: LN + tanh + leaf, one wave per (child, b) ----
    int nPairs = Pc * 16;
    for (int pr2 = tw; pr2 < nPairs; pr2 += 512) {
      int ch = pr2 >> 3, b = pr2 & 7;
      int p = ch >> 1, cg = ch & 1;
      size_t si = (((size_t)p * 128 + cg * 64 + lane) * 8 + b) * 2;
      float ssum = pstat[si], ssq = pstat[si + 1];
#pragma unroll
      for (int d = 1; d < 64; d <<= 1) {
        ssum += __shfl_xor(ssum, d);
        ssq += __shfl_xor(ssq, d);
      }
      float mu = ssum * (1.f / 1024.f);
      float var = ssq * (1.f / 1024.f) - mu * mu;
      float rs = rsqrtf(var + 1e-5f);
      int j0 = lane * 16;
      size_t zr = ((size_t)(p * Bb + b)) * 2048 + cg * 1024 + j0;
      float d0 = 0.f, d1 = 0.f;
      unsigned short yb[16];
#pragma unroll
      for (int g2 = 0; g2 < 4; g2++) {
        f4 z = *(const f4*)&zbuf[zr + g2 * 4];
        f4 lg = *(const f4*)&lng[j0 + g2 * 4];
        f4 lb = *(const f4*)&lnb[j0 + g2 * 4];
        f4 y;
        y.x = tanhf((z.x - mu) * rs * lg.x + lb.x);
        y.y = tanhf((z.y - mu) * rs * lg.y + lb.y);
        y.z = tanhf((z.z - mu) * rs * lg.z + lb.z);
        y.w = tanhf((z.w - mu) * rs * lg.w + lb.w);
        f4 wA = *(const f4*)&Wl[(j0 + g2 * 4) * 2];
        f4 wB = *(const f4*)&Wl[(j0 + g2 * 4) * 2 + 4];
        d0 += y.x * wA.x + y.y * wA.z + y.z * wB.x + y.w * wB.z;
        d1 += y.x * wA.y + y.y * wA.w + y.z * wB.y + y.w * wB.w;
        yb[g2 * 4 + 0] = f2bf(y.x);
        yb[g2 * 4 + 1] = f2bf(y.y);
        yb[g2 * 4 + 2] = f2bf(y.z);
        yb[g2 * 4 + 3] = f2bf(y.w);
      }
      us8 o0, o1;
#pragma unroll
      for (int q2 = 0; q2 < 8; q2++) { o0[q2] = yb[q2]; o1[q2] = yb[8 + q2]; }
      size_t hb = ((size_t)(off + ch) * Bb + b) * Hd + j0;
      *(us8*)&hiddb[hb] = o0;
      *(us8*)&hiddb[hb + 8] = o1;
#pragma unroll
      for (int d = 1; d < 64; d <<= 1) {
        d0 += __shfl_xor(d0, d);
        d1 += __shfl_xor(d1, d);
      }
      if (lane == 0) {
        float l0 = d0 + bl[0], l1 = d1 + bl[1];
        float mm = fmaxf(l0, l1);
        float L = logf(expf(l0 - mm) + expf(l1 - mm));
        int gp = DS.parRows[l - 1][p];
        float half = 0.5f * leaves[((size_t)gp * Bb + b) * 2 + 1];
        leaves[((size_t)(off + ch) * Bb + b) * 2 + 0] = half + l0 - mm - L;
        leaves[((size_t)(off + ch) * Bb + b) * 2 + 1] = half + l1 - mm - L;
      }
    }
    gbar(bar, 128);
  }
}

// ----------------- big bf16 MFMA GEMM + fused softmax partials --------------
constexpr int MT_TILES = 22;           // Mt/128
constexpr int NWG = MT_TILES * NT;     // 5500

template <int BF>
__global__ __launch_bounds__(256) void k_gemm(
    const unsigned short* __restrict__ A, const unsigned short* __restrict__ Bt,
    const float* __restrict__ bout, float* __restrict__ outf,
    unsigned short* __restrict__ lgt, float2* __restrict__ ptile, int Mvalid) {
  __shared__ short As[128 * 64];
  __shared__ short Bs[128 * 64];
  int tid = threadIdx.x;
  int lane = tid & 63, w = tid >> 6;
  int wm = w & 1, wn = w >> 1;
  int bid = blockIdx.x;
  constexpr int q = NWG >> 3, r = NWG & 7;
  int xcd = bid & 7, idx = bid >> 3;
  int wgid = (xcd < r ? xcd * (q + 1) : r * (q + 1) + (xcd - r) * q) + idx;
  int ny = wgid / MT_TILES;
  int mx = wgid - ny * MT_TILES;
  int R0 = mx * 128, C0 = ny * 128;
  f32x4 acc[4][4];
#pragma unroll
  for (int i = 0; i < 4; i++)
#pragma unroll
    for (int j = 0; j < 4; j++) acc[i][j] = 0.f;
  int quad = lane >> 4, l15 = lane & 15;
  int srow = lane >> 3;
  int kc = lane & 7;
  for (int kb = 0; kb < 16; kb++) {
    int k0 = kb * 64;
#pragma unroll
    for (int i = 0; i < 4; i++) {
      int rowb = w * 32 + i * 8;
      int m = rowb + srow;
      int kcx = kc ^ (m & 7);
      const unsigned short* ga = A + (size_t)(R0 + m) * Hd + k0 + kcx * 8;
      const unsigned short* gb = Bt + (size_t)(C0 + m) * Hd + k0 + kcx * 8;
      __builtin_amdgcn_global_load_lds(
          (__attribute__((address_space(1))) void*)ga,
          (__attribute__((address_space(3))) void*)&As[rowb * 64], 16, 0, 0);
      __builtin_amdgcn_global_load_lds(
          (__attribute__((address_space(1))) void*)gb,
          (__attribute__((address_space(3))) void*)&Bs[rowb * 64], 16, 0, 0);
    }
    __syncthreads();
#pragma unroll
    for (int ksi = 0; ksi < 2; ksi++) {
      bf16x8 af[4], bfr[4];
      int kidx = ksi * 4 + quad;
#pragma unroll
      for (int i = 0; i < 4; i++) {
        int m = wm * 64 + i * 16 + l15;
        af[i] = *(const bf16x8*)&As[m * 64 + (kidx ^ (m & 7)) * 8];
      }
#pragma unroll
      for (int j = 0; j < 4; j++) {
        int n = wn * 64 + j * 16 + l15;
        bfr[j] = *(const bf16x8*)&Bs[n * 64 + (kidx ^ (n & 7)) * 8];
      }
#pragma unroll
      for (int i = 0; i < 4; i++)
#pragma unroll
        for (int j = 0; j < 4; j++)
          acc[i][j] = __builtin_amdgcn_mfma_f32_16x16x32_bf16(af[i], bfr[j],
                                                              acc[i][j], 0, 0, 0);
    }
    __syncthreads();
  }
  float2* s0 = (float2*)As;
  float2* s1 = (float2*)Bs;
  float2* sw = wn ? s1 : s0;
  float bo[4];
#pragma unroll
  for (int j = 0; j < 4; j++) bo[j] = bout[C0 + wn * 64 + j * 16 + l15];
#pragma unroll
  for (int i = 0; i < 4; i++) {
#pragma unroll
    for (int r2 = 0; r2 < 4; r2++) {
      int lr = wm * 64 + i * 16 + quad * 4 + r2;
      int row = R0 + lr;
      float v0 = acc[i][0][r2] + bo[0];
      float v1 = acc[i][1][r2] + bo[1];
      float v2 = acc[i][2][r2] + bo[2];
      float v3 = acc[i][3][r2] + bo[3];
      if (row < Mvalid) {
        size_t base = (size_t)row * Vv + C0 + wn * 64 + l15;
        if (BF) {
          __builtin_nontemporal_store(f2bf(v0), &lgt[base + 0]);
          __builtin_nontemporal_store(f2bf(v1), &lgt[base + 16]);
          __builtin_nontemporal_store(f2bf(v2), &lgt[base + 32]);
          __builtin_nontemporal_store(f2bf(v3), &lgt[base + 48]);
        } else {
          __builtin_nontemporal_store(v0, &outf[base + 0]);
          __builtin_nontemporal_store(v1, &outf[base + 16]);
          __builtin_nontemporal_store(v2, &outf[base + 32]);
          __builtin_nontemporal_store(v3, &outf[base + 48]);
        }
      }
      float mx4 = fmaxf(fmaxf(v0, v1), fmaxf(v2, v3));
      float sm4 = exp2f((v0 - mx4) * L2E) + exp2f((v1 - mx4) * L2E) +
                  exp2f((v2 - mx4) * L2E) + exp2f((v3 - mx4) * L2E);
      float2 e; e.x = mx4; e.y = sm4;
      sw[lr * 16 + l15] = e;
    }
  }
  __syncthreads();
  if (tid < 128) {
    int rot = tid & 15;
    float M = -3e38f;
#pragma unroll
    for (int t = 0; t < 16; t++) {
      int c = (t + rot) & 15;
      M = fmaxf(M, fmaxf(s0[tid * 16 + c].x, s1[tid * 16 + c].x));
    }
    float S = 0.f;
#pragma unroll
    for (int t = 0; t < 16; t++) {
      int c = (t + rot) & 15;
      float2 a = s0[tid * 16 + c], b = s1[tid * 16 + c];
      S += a.y * exp2f((a.x - M) * L2E) + b.y * exp2f((b.x - M) * L2E);
    }
    float2 o; o.x = M; o.y = S;
    ptile[(size_t)(R0 + tid) * NT + ny] = o;
  }
}

// --------------------- reduce partial stats -> row LSE ----------------------
__global__ void k_lse(const float2* __restrict__ ptile, float* __restrict__ st) {
  __shared__ float ms[256], ss[256];
  int r = blockIdx.x, tid = threadIdx.x;
  float mx = -3e38f, sm = 0.f;
  for (int t = tid; t < NT; t += 256) {
    float2 e = ptile[(size_t)r * NT + t];
    float M = fmaxf(mx, e.x);
    sm = sm * exp2f((mx - M) * L2E) + e.y * exp2f((e.x - M) * L2E);
    mx = M;
  }
  ms[tid] = mx; ss[tid] = sm;
  __syncthreads();
  for (int o = 128; o; o >>= 1) {
    if (tid < o) {
      float m2 = ms[tid + o], s2 = ss[tid + o];
      float M = fmaxf(ms[tid], m2);
      ss[tid] = ss[tid] * exp2f((ms[tid] - M) * L2E) + s2 * exp2f((m2 - M) * L2E);
      ms[tid] = M;
    }
    __syncthreads();
  }
  if (tid == 0) st[r] = ms[0] + logf(ss[0]);
}

// ------------------- normalize: fp32 in place (fallback) --------------------
__global__ void k_norm(float* __restrict__ out, const float* __restrict__ st) {
  int r = blockIdx.y;
  int i = blockIdx.x * 256 + threadIdx.x;
  if (i < Vv / 4) {
    float sub = st[r];
    f4* p = (f4*)(out + (size_t)r * Vv) + i;
    f4 v = __builtin_nontemporal_load(p);
    v -= sub;
    __builtin_nontemporal_store(v, p);
  }
}

// ------------------- normalize: bf16 logits -> fp32 out ---------------------
__global__ void k_norm_bf(const unsigned short* __restrict__ lgt,
                          float* __restrict__ out, const float* __restrict__ st) {
  int r = blockIdx.y;
  int i = blockIdx.x * 256 + threadIdx.x;
  if (i < Vv / 8) {
    float sub = st[r];
    us8 v = __builtin_nontemporal_load((const us8*)(lgt + (size_t)r * Vv + i * 8));
    f4 o0, o1;
#pragma unroll
    for (int qk = 0; qk < 4; qk++) {
      union { unsigned u; float f; } cv;
      cv.u = ((unsigned)v[qk]) << 16;
      o0[qk] = cv.f - sub;
    }
#pragma unroll
    for (int qk = 0; qk < 4; qk++) {
      union { unsigned u; float f; } cv;
      cv.u = ((unsigned)v[4 + qk]) << 16;
      o1[qk] = cv.f - sub;
    }
    float* p = out + (size_t)r * Vv + i * 8;
    __builtin_nontemporal_store(o0, (f4*)p);
    __builtin_nontemporal_store(o1, (f4*)(p + 4));
  }
}

// ------------------------- static index outputs -----------------------------
__global__ void k_idx(float* __restrict__ dst) {
  int total = DS.nStart + DS.nEnd + 2 * DS.nS;
  for (int i = threadIdx.x; i < total; i += 256) {
    int v;
    if (i < DS.nStart) v = DS.startIdx[i];
    else if (i < DS.nStart + DS.nEnd) v = DS.endIdx[i - DS.nStart];
    else if (i < DS.nStart + DS.nEnd + DS.nS) v = DS.sOut[i - DS.nStart - DS.nEnd];
    else v = DS.sIn[i - DS.nStart - DS.nEnd - DS.nS];
    dst[i] = (float)v;
  }
}

// ---------------------------------------------------------------------------
extern "C" void kernel_launch(void* const* d_in, const int* in_sizes, int n_in,
                              void* d_out, int out_size, void* d_ws, size_t ws_size,
                              hipStream_t stream) {
  (void)in_sizes; (void)n_in; (void)out_size;
  const float* x    = (const float*)d_in[0];
  const float* Win  = (const float*)d_in[1];
  const float* bin  = (const float*)d_in[2];
  const float* Wg   = (const float*)d_in[3];
  const float* bg   = (const float*)d_in[4];
  const float* Wc   = (const float*)d_in[5];
  const float* bc   = (const float*)d_in[6];
  const float* lng  = (const float*)d_in[7];
  const float* lnb  = (const float*)d_in[8];
  const float* Wl   = (const float*)d_in[9];
  const float* bl   = (const float*)d_in[10];
  const float* Wout = (const float*)d_in[11];
  const float* bout = (const float*)d_in[12];
  float* out = (float*)d_out;

  constexpr int T = HS.T;                          // 351
  constexpr int Mrows = T * Bb;                    // 2808
  constexpr int Mt = ((Mrows + 127) / 128) * 128;  // 2816

  char* ws = (char*)d_ws;
  char* ws0 = ws;
  unsigned short* Wt = (unsigned short*)ws;    ws += (size_t)Vv * Hd * 2;
  unsigned short* Wct = (unsigned short*)ws;   ws += (size_t)2048 * Hd * 2;
  float* hidd = (float*)ws;                    ws += (size_t)Bb * Hd * 4;   // leaf0 only
  unsigned short* hiddb = (unsigned short*)ws; ws += (size_t)Mt * Hd * 2;
  float* gbuf = (float*)ws;                    ws += (size_t)Bb * Hd * 4;
  float* gW = (float*)ws;                      ws += (size_t)Bb * 2048 * 4;
  float* zbuf = (float*)ws;                    ws += (size_t)256 * 2048 * 4;
  float* pstat = (float*)ws;                   ws += (size_t)MAXP * 128 * 8 * 2 * 4;
  int* bar = (int*)ws;                         ws += 64;
  float2* ptile = (float2*)ws;                 ws += (size_t)Mt * NT * 8;
  float* st = (float*)ws;                      ws += (size_t)Mt * 4;
  unsigned short* lgt = (unsigned short*)ws;   // optional, gated on ws_size
  size_t needBf = (size_t)(ws - ws0) + (size_t)Mt * Vv * 2;
  bool bfp = ws_size >= needBf;

  float* leaves = out + (size_t)Mrows * Vv;
  float* idxdst = leaves + (size_t)Mrows * 2;

  hipMemsetAsync(bar, 0, 8, stream);
  k_wct<<<dim3(2048 / 32, Hd / 32), dim3(32, 8), 0, stream>>>(Wc, Wct);
  k_init<<<dim3(8, 2), dim3(256), 0, stream>>>(x, Wg, bg, Win, bin, gbuf, hidd, hiddb);
  k_gw<<<dim3(16), dim3(256), 0, stream>>>(gbuf, Wc, bc, gW);
  k_leaf0<<<dim3(1), dim3(512), 0, stream>>>(hidd, Wl, bl, leaves);

  k_tree<<<dim3(256), dim3(256), 0, stream>>>(hiddb, Wct, gW, lng, lnb, Wl, bl,
                                              leaves, zbuf, pstat, bar, Wout, Wt);

  if (bfp) {
    k_gemm<1><<<dim3(NWG), dim3(256), 0, stream>>>(hiddb, Wt, bout, out, lgt,
                                                   ptile, Mrows);
    k_lse<<<dim3(Mrows), dim3(256), 0, stream>>>(ptile, st);
    k_norm_bf<<<dim3(16, Mrows), dim3(256), 0, stream>>>(lgt, out, st);
  } else {
    k_gemm<0><<<dim3(NWG), dim3(256), 0, stream>>>(hiddb, Wt, bout, out, lgt,
                                                   ptile, Mrows);
    k_lse<<<dim3(Mrows), dim3(256), 0, stream>>>(ptile, st);
    k_norm<<<dim3(32, Mrows), dim3(256), 0, stream>>>(out, st);
  }
  k_idx<<<dim3(1), dim3(256), 0, stream>>>(idxdst);
}

// Round 5
// 1713.710 us; speedup vs baseline: 1.1135x; 1.1135x over previous
//
#include <hip/hip_runtime.h>
#include <cstdint>
#include <cstddef>

// ---------------------------------------------------------------------------
// OrderedMemoryDecoder (DEPTH=14, B=8, H=1024, V=32000) for gfx950.
// R6: persistent tree kernel, phase A restored to the proven k_cellg
// LDS-staged MFMA tile (global_load_lds + XOR swizzle), job-looped per block;
// phase B per-wave LN+tanh+leaf sums the 4 K-split partials + gW.
// W_out transpose overlapped on blocks 128-255. k_gemm/lse/norm_bf as R4.
// ---------------------------------------------------------------------------

typedef __attribute__((ext_vector_type(4))) float   f4;
typedef __attribute__((ext_vector_type(4))) float   f32x4;
typedef __attribute__((ext_vector_type(8))) __bf16  bf16x8;
typedef __attribute__((ext_vector_type(4))) unsigned short us4;
typedef __attribute__((ext_vector_type(8))) unsigned short us8;

constexpr int DEPTH = 14;
constexpr int Bb = 8;
constexpr int Hd = 1024;
constexpr int Vv = 32000;
constexpr int NT = Vv / 128;   // 250 N-tiles in big GEMM
constexpr int MAXT = 512;
constexpr int MAXS = 4096;
constexpr int MAXP = 32;
constexpr float L2E = 1.44269504088896340736f;

struct SB {
  int lvlOff[DEPTH + 1];
  int lvlK[DEPTH];
  int len[MAXT];
  int lch[MAXT], rch[MAXT];
  int parCnt[DEPTH];
  int parRows[DEPTH][MAXP];
  int T;
  int nS;
  int sOut[MAXS], sIn[MAXS];
  int nStart, nEnd;
  int startIdx[16], endIdx[16];
};

constexpr int ceil75(int L) {
  constexpr int t[14] = {0, 1, 2, 3, 3, 4, 4, 5, 5, 6, 6, 7, 7, 7};
  return t[L];
}

constexpr SB build() {
  SB s{};
  for (int i = 0; i < MAXT; i++) { s.lch[i] = -1; s.rch[i] = -1; }
  s.lvlOff[0] = 0; s.lvlK[0] = 1; s.len[0] = DEPTH;
  for (int l = 0; l < DEPTH - 1; l++) {
    int off = s.lvlOff[l], K = s.lvlK[l];
    int nxt = off + K, cnt = 0;
    for (int i = 0; i < K; i++) {
      int g = off + i;
      if (s.len[g] > 1) {
        int gl = nxt + 2 * cnt, gr = gl + 1;
        s.lch[g] = gl; s.rch[g] = gr;
        s.len[gl] = ceil75(s.len[g] - 1);
        s.len[gr] = s.len[g] - 1;
        s.parRows[l][cnt] = g;
        cnt++;
      }
    }
    s.parCnt[l] = cnt;
    s.lvlOff[l + 1] = nxt;
    s.lvlK[l + 1] = 2 * cnt;
  }
  s.T = s.lvlOff[DEPTH - 1] + s.lvlK[DEPTH - 1];
  s.nS = 0;
  for (int l = DEPTH - 2; l >= 0; l--) {
    for (int pi = 0; pi < s.parCnt[l]; pi++) {
      int g = s.parRows[l][pi];
      for (int u = s.lch[g]; u != -1; u = s.rch[u])
        for (int v = s.rch[g]; v != -1; v = s.lch[v]) {
          s.sOut[s.nS] = u; s.sIn[s.nS] = v; s.nS++;
        }
    }
  }
  s.nStart = 0;
  for (int u = 0; u != -1; u = s.lch[u]) s.startIdx[s.nStart++] = u;
  s.nEnd = 0;
  for (int u = 0; u != -1; u = s.rch[u]) s.endIdx[s.nEnd++] = u;
  return s;
}

constexpr SB HS = build();
__device__ const SB DS = build();

__device__ __forceinline__ unsigned short f2bf(float f) {
  union { float f; unsigned u; } v; v.f = f;
  unsigned r = v.u + 0x7fffu + ((v.u >> 16) & 1u);  // RNE
  return (unsigned short)(r >> 16);
}

// ----------------- device-scope grid barrier (tree-role blocks) -------------
__device__ __forceinline__ void gbar(int* bar, int nblk) {
  __syncthreads();
  __threadfence();                       // release our data writes
  if (threadIdx.x == 0) {
    int g = __hip_atomic_load(&bar[1], __ATOMIC_ACQUIRE, __HIP_MEMORY_SCOPE_AGENT);
    int a = __hip_atomic_fetch_add(&bar[0], 1, __ATOMIC_ACQ_REL,
                                   __HIP_MEMORY_SCOPE_AGENT);
    if (a == nblk - 1) {
      __hip_atomic_store(&bar[0], 0, __ATOMIC_RELAXED, __HIP_MEMORY_SCOPE_AGENT);
      __hip_atomic_fetch_add(&bar[1], 1, __ATOMIC_ACQ_REL,
                             __HIP_MEMORY_SCOPE_AGENT);
    } else {
      while (__hip_atomic_load(&bar[1], __ATOMIC_ACQUIRE,
                               __HIP_MEMORY_SCOPE_AGENT) == g) {
        __builtin_amdgcn_s_sleep(8);
      }
    }
  }
  __syncthreads();
}

// --------------- W_cell[:1024,:] -> bf16, transposed [2048][1024] -----------
__global__ void k_wct(const float* __restrict__ Wc,
                      unsigned short* __restrict__ Wct) {
  __shared__ float t[32][33];
  int tx = threadIdx.x, ty = threadIdx.y;
  int n0 = blockIdx.x * 32, k0 = blockIdx.y * 32;
  for (int i = 0; i < 4; i++)
    t[ty + 8 * i][tx] = Wc[(size_t)(k0 + ty + 8 * i) * 2048 + n0 + tx];
  __syncthreads();
  for (int i = 0; i < 4; i++)
    Wct[(size_t)(n0 + ty + 8 * i) * Hd + k0 + tx] = f2bf(t[tx][ty + 8 * i]);
}

// ------------------------------ g and h0 ------------------------------------
__global__ void k_init(const float* __restrict__ x, const float* __restrict__ Wg,
                       const float* __restrict__ bg, const float* __restrict__ Win,
                       const float* __restrict__ bin, float* __restrict__ gbuf,
                       float* __restrict__ hidd, unsigned short* __restrict__ hiddb) {
  __shared__ float xs[Bb * Hd];
  __shared__ float part[Bb][128];
  int tid = threadIdx.x;
  int mat = blockIdx.y;
  const float* W = mat ? Win : Wg;
  const float* bias = mat ? bin : bg;
  for (int i = tid; i < Bb * Hd; i += 256) xs[i] = x[i];
  __syncthreads();
  int c = tid & 127, kh = tid >> 7;
  int col = blockIdx.x * 128 + c;
  float acc[Bb];
#pragma unroll
  for (int b = 0; b < Bb; b++) acc[b] = 0.f;
  for (int k = kh * 512; k < kh * 512 + 512; k++) {
    float w = W[(size_t)k * Hd + col];
#pragma unroll
    for (int b = 0; b < Bb; b++) acc[b] += xs[b * Hd + k] * w;
  }
  if (kh == 1)
    for (int b = 0; b < Bb; b++) part[b][c] = acc[b];
  __syncthreads();
  if (kh == 0) {
    for (int b = 0; b < Bb; b++) {
      float v = acc[b] + part[b][c] + bias[col];
      if (mat == 0) gbuf[b * Hd + col] = v;
      else { hidd[(size_t)b * Hd + col] = v; hiddb[(size_t)b * Hd + col] = f2bf(v); }
    }
  }
}

// --------------------- gW = g @ W_cell[1024:,:] + b_cell --------------------
__global__ void k_gw(const float* __restrict__ gbuf, const float* __restrict__ Wc,
                     const float* __restrict__ bc, float* __restrict__ gW) {
  __shared__ float xs[Bb * Hd];
  __shared__ float part[Bb][128];
  int tid = threadIdx.x;
  for (int i = tid; i < Bb * Hd; i += 256) xs[i] = gbuf[i];
  __syncthreads();
  int c = tid & 127, kh = tid >> 7;
  int col = blockIdx.x * 128 + c;
  float acc[Bb];
#pragma unroll
  for (int b = 0; b < Bb; b++) acc[b] = 0.f;
  for (int k = kh * 512; k < kh * 512 + 512; k++) {
    float w = Wc[(size_t)(Hd + k) * 2048 + col];
#pragma unroll
    for (int b = 0; b < Bb; b++) acc[b] += xs[b * Hd + k] * w;
  }
  if (kh == 1)
    for (int b = 0; b < Bb; b++) part[b][c] = acc[b];
  __syncthreads();
  if (kh == 0)
    for (int b = 0; b < Bb; b++)
      gW[(size_t)b * 2048 + col] = acc[b] + part[b][c] + bc[col];
}

// ---------------------- level-0 leaf log-softmax ----------------------------
__global__ void k_leaf0(const float* __restrict__ hidd, const float* __restrict__ Wl,
                        const float* __restrict__ bl, float* __restrict__ leaves) {
  int b = threadIdx.x >> 6, lane = threadIdx.x & 63;
  float d0 = 0.f, d1 = 0.f;
  for (int k = lane; k < Hd; k += 64) {
    float h = hidd[(size_t)b * Hd + k];
    d0 += h * Wl[2 * k];
    d1 += h * Wl[2 * k + 1];
  }
  for (int off = 32; off; off >>= 1) {
    d0 += __shfl_down(d0, off);
    d1 += __shfl_down(d1, off);
  }
  if (lane == 0) {
    float l0 = d0 + bl[0], l1 = d1 + bl[1];
    float m = fmaxf(l0, l1);
    float L = logf(expf(l0 - m) + expf(l1 - m));
    leaves[b * 2 + 0] = l0 - m - L;
    leaves[b * 2 + 1] = l1 - m - L;
  }
}

// -------------------- persistent tree + W_out transpose ---------------------
// blocks 0..127: per level: phase A = job-looped k_cellg tile (LDS-staged
// MFMA, K split x4 -> zbuf partials); gbar; phase B = per-wave sum partials
// + gW, LN+tanh, bf16 h write, leaf log-softmax; gbar.
// blocks 128..255: W_out -> bf16 transposed (grid-stride 128x64 tiles).
struct ShG { short As[128 * 64]; short Bs[128 * 64]; };
union ShU { ShG g; float tsh[64][129]; };

__global__ __launch_bounds__(256) void k_tree(
    unsigned short* __restrict__ hiddb, const unsigned short* __restrict__ Wct,
    const float* __restrict__ gW, const float* __restrict__ lng,
    const float* __restrict__ lnb, const float* __restrict__ Wl,
    const float* __restrict__ bl, float* __restrict__ leaves,
    float* __restrict__ zbuf, int* __restrict__ bar,
    const float* __restrict__ Wout, unsigned short* __restrict__ Wt) {
  __shared__ ShU sh;
  int tid = threadIdx.x;
  if (blockIdx.x >= 128) {
    // ------------------------- W_out transpose role -------------------------
    for (int tile = blockIdx.x - 128; tile < 250 * 16; tile += 128) {
      int n0 = (tile % 250) * 128, k0 = (tile / 250) * 64;
#pragma unroll
      for (int i = 0; i < 8; i++) {
        int k = (tid >> 5) + 8 * i;
        int c = (tid & 31) * 4;
        f4 v = *(const f4*)&Wout[(size_t)(k0 + k) * Vv + n0 + c];
        sh.tsh[k][c] = v.x; sh.tsh[k][c + 1] = v.y;
        sh.tsh[k][c + 2] = v.z; sh.tsh[k][c + 3] = v.w;
      }
      __syncthreads();
#pragma unroll
      for (int pass = 0; pass < 4; pass++) {
        int n = (tid >> 3) + 32 * pass;
        int ks = (tid & 7) * 8;
        us8 o;
#pragma unroll
        for (int q2 = 0; q2 < 8; q2++) o[q2] = f2bf(sh.tsh[ks + q2][n]);
        *(us8*)&Wt[(size_t)(n0 + n) * Hd + k0 + ks] = o;
      }
      __syncthreads();
    }
    return;
  }
  // ------------------------------ tree role ---------------------------------
  int w = tid >> 6, lane = tid & 63;
  int wm = w & 1, wn = w >> 1;
  int quad = lane >> 4, l15 = lane & 15;
  int srow = lane >> 3, kc = lane & 7;
  int tw = blockIdx.x * 4 + w;          // 0..511
  for (int l = 1; l < DEPTH; l++) {
    int Pc = DS.parCnt[l - 1];
    int Mtot = Pc * Bb;
    int Mtiles = (Mtot + 127) >> 7;
    int off = DS.lvlOff[l];
    // ---- phase A: LDS-staged tile GEMM jobs (mt, ct, ks2) ----
    int nJobs = Mtiles * 64;
    for (int jid = blockIdx.x; jid < nJobs; jid += 128) {
      int ks2 = jid & 3, ct = (jid >> 2) & 15, mt = jid >> 6;
      int R0 = mt * 128, C0 = ct * 128;
      f32x4 acc[4][4];
#pragma unroll
      for (int i = 0; i < 4; i++)
#pragma unroll
        for (int j = 0; j < 4; j++) acc[i][j] = 0.f;
      for (int kb = ks2 * 4; kb < ks2 * 4 + 4; kb++) {
        int k0 = kb * 64;
#pragma unroll
        for (int i = 0; i < 4; i++) {
          int rowb = w * 32 + i * 8;
          int m = rowb + srow;
          int kcx = kc ^ (m & 7);
          int gr = R0 + m;
          int grc = gr < Mtot ? gr : 0;
          int arow = DS.parRows[l - 1][grc >> 3] * Bb + (grc & 7);
          const unsigned short* ga = hiddb + (size_t)arow * Hd + k0 + kcx * 8;
          const unsigned short* gb = Wct + (size_t)(C0 + m) * Hd + k0 + kcx * 8;
          __builtin_amdgcn_global_load_lds(
              (__attribute__((address_space(1))) void*)ga,
              (__attribute__((address_space(3))) void*)&sh.g.As[rowb * 64],
              16, 0, 0);
          __builtin_amdgcn_global_load_lds(
              (__attribute__((address_space(1))) void*)gb,
              (__attribute__((address_space(3))) void*)&sh.g.Bs[rowb * 64],
              16, 0, 0);
        }
        __syncthreads();
#pragma unroll
        for (int ksi = 0; ksi < 2; ksi++) {
          bf16x8 af[4], bfr[4];
          int kidx = ksi * 4 + quad;
#pragma unroll
          for (int i = 0; i < 4; i++) {
            int m = wm * 64 + i * 16 + l15;
            af[i] = *(const bf16x8*)&sh.g.As[m * 64 + (kidx ^ (m & 7)) * 8];
          }
#pragma unroll
          for (int j = 0; j < 4; j++) {
            int n = wn * 64 + j * 16 + l15;
            bfr[j] = *(const bf16x8*)&sh.g.Bs[n * 64 + (kidx ^ (n & 7)) * 8];
          }
#pragma unroll
          for (int i = 0; i < 4; i++)
#pragma unroll
            for (int j = 0; j < 4; j++)
              acc[i][j] = __builtin_amdgcn_mfma_f32_16x16x32_bf16(
                  af[i], bfr[j], acc[i][j], 0, 0, 0);
        }
        __syncthreads();
      }
#pragma unroll
      for (int j = 0; j < 4; j++) {
        int col = C0 + wn * 64 + j * 16 + l15;
#pragma unroll
        for (int i = 0; i < 4; i++) {
          int rowb = R0 + wm * 64 + i * 16 + quad * 4;
#pragma unroll
          for (int r = 0; r < 4; r++) {
            int row = rowb + r;
            if (row < Mtot)
              zbuf[((size_t)ks2 * 256 + row) * 2048 + col] = acc[i][j][r];
          }
        }
      }
    }
    gbar(bar, 128);
    // ---- phase B: LN + tanh + leaf, one wave per (child, b) ----
    int nPairs = Pc * 16;
    for (int pr2 = tw; pr2 < nPairs; pr2 += 512) {
      int ch = pr2 >> 3, b = pr2 & 7;
      int p = ch >> 1, cg = ch & 1;
      int j0 = lane * 16;
      size_t zr = ((size_t)(p * Bb + b)) * 2048 + cg * 1024 + j0;
      f4 z[4];
      float s1 = 0.f, s2 = 0.f;
#pragma unroll
      for (int g2 = 0; g2 < 4; g2++) {
        f4 zz = *(const f4*)&zbuf[zr + g2 * 4];
        zz += *(const f4*)&zbuf[zr + g2 * 4 + (size_t)256 * 2048];
        zz += *(const f4*)&zbuf[zr + g2 * 4 + (size_t)512 * 2048];
        zz += *(const f4*)&zbuf[zr + g2 * 4 + (size_t)768 * 2048];
        zz += *(const f4*)&gW[(size_t)b * 2048 + cg * 1024 + j0 + g2 * 4];
        z[g2] = zz;
        s1 += zz.x + zz.y + zz.z + zz.w;
        s2 += zz.x * zz.x + zz.y * zz.y + zz.z * zz.z + zz.w * zz.w;
      }
#pragma unroll
      for (int d = 1; d < 64; d <<= 1) {
        s1 += __shfl_xor(s1, d);
        s2 += __shfl_xor(s2, d);
      }
      float mu = s1 * (1.f / 1024.f);
      float var = s2 * (1.f / 1024.f) - mu * mu;
      float rs = rsqrtf(var + 1e-5f);
      float d0 = 0.f, d1 = 0.f;
      unsigned short yb[16];
#pragma unroll
      for (int g2 = 0; g2 < 4; g2++) {
        f4 lg = *(const f4*)&lng[j0 + g2 * 4];
        f4 lb = *(const f4*)&lnb[j0 + g2 * 4];
        f4 y;
        y.x = tanhf((z[g2].x - mu) * rs * lg.x + lb.x);
        y.y = tanhf((z[g2].y - mu) * rs * lg.y + lb.y);
        y.z = tanhf((z[g2].z - mu) * rs * lg.z + lb.z);
        y.w = tanhf((z[g2].w - mu) * rs * lg.w + lb.w);
        f4 wA = *(const f4*)&Wl[(j0 + g2 * 4) * 2];
        f4 wB = *(const f4*)&Wl[(j0 + g2 * 4) * 2 + 4];
        d0 += y.x * wA.x + y.y * wA.z + y.z * wB.x + y.w * wB.z;
        d1 += y.x * wA.y + y.y * wA.w + y.z * wB.y + y.w * wB.w;
        yb[g2 * 4 + 0] = f2bf(y.x);
        yb[g2 * 4 + 1] = f2bf(y.y);
        yb[g2 * 4 + 2] = f2bf(y.z);
        yb[g2 * 4 + 3] = f2bf(y.w);
      }
      us8 o0, o1;
#pragma unroll
      for (int q2 = 0; q2 < 8; q2++) { o0[q2] = yb[q2]; o1[q2] = yb[8 + q2]; }
      size_t hb = ((size_t)(off + ch) * Bb + b) * Hd + j0;
      *(us8*)&hiddb[hb] = o0;
      *(us8*)&hiddb[hb + 8] = o1;
#pragma unroll
      for (int d = 1; d < 64; d <<= 1) {
        d0 += __shfl_xor(d0, d);
        d1 += __shfl_xor(d1, d);
      }
      if (lane == 0) {
        float l0 = d0 + bl[0], l1 = d1 + bl[1];
        float mm = fmaxf(l0, l1);
        float L = logf(expf(l0 - mm) + expf(l1 - mm));
        int gp = DS.parRows[l - 1][p];
        float half = 0.5f * leaves[((size_t)gp * Bb + b) * 2 + 1];
        leaves[((size_t)(off + ch) * Bb + b) * 2 + 0] = half + l0 - mm - L;
        leaves[((size_t)(off + ch) * Bb + b) * 2 + 1] = half + l1 - mm - L;
      }
    }
    gbar(bar, 128);
  }
}

// ----------------- big bf16 MFMA GEMM + fused softmax partials --------------
constexpr int MT_TILES = 22;           // Mt/128
constexpr int NWG = MT_TILES * NT;     // 5500

template <int BF>
__global__ __launch_bounds__(256) void k_gemm(
    const unsigned short* __restrict__ A, const unsigned short* __restrict__ Bt,
    const float* __restrict__ bout, float* __restrict__ outf,
    unsigned short* __restrict__ lgt, float2* __restrict__ ptile, int Mvalid) {
  __shared__ short As[128 * 64];
  __shared__ short Bs[128 * 64];
  int tid = threadIdx.x;
  int lane = tid & 63, w = tid >> 6;
  int wm = w & 1, wn = w >> 1;
  int bid = blockIdx.x;
  constexpr int q = NWG >> 3, r = NWG & 7;
  int xcd = bid & 7, idx = bid >> 3;
  int wgid = (xcd < r ? xcd * (q + 1) : r * (q + 1) + (xcd - r) * q) + idx;
  int ny = wgid / MT_TILES;
  int mx = wgid - ny * MT_TILES;
  int R0 = mx * 128, C0 = ny * 128;
  f32x4 acc[4][4];
#pragma unroll
  for (int i = 0; i < 4; i++)
#pragma unroll
    for (int j = 0; j < 4; j++) acc[i][j] = 0.f;
  int quad = lane >> 4, l15 = lane & 15;
  int srow = lane >> 3;
  int kc = lane & 7;
  for (int kb = 0; kb < 16; kb++) {
    int k0 = kb * 64;
#pragma unroll
    for (int i = 0; i < 4; i++) {
      int rowb = w * 32 + i * 8;
      int m = rowb + srow;
      int kcx = kc ^ (m & 7);
      const unsigned short* ga = A + (size_t)(R0 + m) * Hd + k0 + kcx * 8;
      const unsigned short* gb = Bt + (size_t)(C0 + m) * Hd + k0 + kcx * 8;
      __builtin_amdgcn_global_load_lds(
          (__attribute__((address_space(1))) void*)ga,
          (__attribute__((address_space(3))) void*)&As[rowb * 64], 16, 0, 0);
      __builtin_amdgcn_global_load_lds(
          (__attribute__((address_space(1))) void*)gb,
          (__attribute__((address_space(3))) void*)&Bs[rowb * 64], 16, 0, 0);
    }
    __syncthreads();
#pragma unroll
    for (int ksi = 0; ksi < 2; ksi++) {
      bf16x8 af[4], bfr[4];
      int kidx = ksi * 4 + quad;
#pragma unroll
      for (int i = 0; i < 4; i++) {
        int m = wm * 64 + i * 16 + l15;
        af[i] = *(const bf16x8*)&As[m * 64 + (kidx ^ (m & 7)) * 8];
      }
#pragma unroll
      for (int j = 0; j < 4; j++) {
        int n = wn * 64 + j * 16 + l15;
        bfr[j] = *(const bf16x8*)&Bs[n * 64 + (kidx ^ (n & 7)) * 8];
      }
#pragma unroll
      for (int i = 0; i < 4; i++)
#pragma unroll
        for (int j = 0; j < 4; j++)
          acc[i][j] = __builtin_amdgcn_mfma_f32_16x16x32_bf16(af[i], bfr[j],
                                                              acc[i][j], 0, 0, 0);
    }
    __syncthreads();
  }
  float2* s0 = (float2*)As;
  float2* s1 = (float2*)Bs;
  float2* sw = wn ? s1 : s0;
  float bo[4];
#pragma unroll
  for (int j = 0; j < 4; j++) bo[j] = bout[C0 + wn * 64 + j * 16 + l15];
#pragma unroll
  for (int i = 0; i < 4; i++) {
#pragma unroll
    for (int r2 = 0; r2 < 4; r2++) {
      int lr = wm * 64 + i * 16 + quad * 4 + r2;
      int row = R0 + lr;
      float v0 = acc[i][0][r2] + bo[0];
      float v1 = acc[i][1][r2] + bo[1];
      float v2 = acc[i][2][r2] + bo[2];
      float v3 = acc[i][3][r2] + bo[3];
      if (row < Mvalid) {
        size_t base = (size_t)row * Vv + C0 + wn * 64 + l15;
        if (BF) {
          __builtin_nontemporal_store(f2bf(v0), &lgt[base + 0]);
          __builtin_nontemporal_store(f2bf(v1), &lgt[base + 16]);
          __builtin_nontemporal_store(f2bf(v2), &lgt[base + 32]);
          __builtin_nontemporal_store(f2bf(v3), &lgt[base + 48]);
        } else {
          __builtin_nontemporal_store(v0, &outf[base + 0]);
          __builtin_nontemporal_store(v1, &outf[base + 16]);
          __builtin_nontemporal_store(v2, &outf[base + 32]);
          __builtin_nontemporal_store(v3, &outf[base + 48]);
        }
      }
      float mx4 = fmaxf(fmaxf(v0, v1), fmaxf(v2, v3));
      float sm4 = exp2f((v0 - mx4) * L2E) + exp2f((v1 - mx4) * L2E) +
                  exp2f((v2 - mx4) * L2E) + exp2f((v3 - mx4) * L2E);
      float2 e; e.x = mx4; e.y = sm4;
      sw[lr * 16 + l15] = e;
    }
  }
  __syncthreads();
  if (tid < 128) {
    int rot = tid & 15;
    float M = -3e38f;
#pragma unroll
    for (int t = 0; t < 16; t++) {
      int c = (t + rot) & 15;
      M = fmaxf(M, fmaxf(s0[tid * 16 + c].x, s1[tid * 16 + c].x));
    }
    float S = 0.f;
#pragma unroll
    for (int t = 0; t < 16; t++) {
      int c = (t + rot) & 15;
      float2 a = s0[tid * 16 + c], b = s1[tid * 16 + c];
      S += a.y * exp2f((a.x - M) * L2E) + b.y * exp2f((b.x - M) * L2E);
    }
    float2 o; o.x = M; o.y = S;
    ptile[(size_t)(R0 + tid) * NT + ny] = o;
  }
}

// --------------------- reduce partial stats -> row LSE ----------------------
__global__ void k_lse(const float2* __restrict__ ptile, float* __restrict__ st) {
  __shared__ float ms[256], ss[256];
  int r = blockIdx.x, tid = threadIdx.x;
  float mx = -3e38f, sm = 0.f;
  for (int t = tid; t < NT; t += 256) {
    float2 e = ptile[(size_t)r * NT + t];
    float M = fmaxf(mx, e.x);
    sm = sm * exp2f((mx - M) * L2E) + e.y * exp2f((e.x - M) * L2E);
    mx = M;
  }
  ms[tid] = mx; ss[tid] = sm;
  __syncthreads();
  for (int o = 128; o; o >>= 1) {
    if (tid < o) {
      float m2 = ms[tid + o], s2 = ss[tid + o];
      float M = fmaxf(ms[tid], m2);
      ss[tid] = ss[tid] * exp2f((ms[tid] - M) * L2E) + s2 * exp2f((m2 - M) * L2E);
      ms[tid] = M;
    }
    __syncthreads();
  }
  if (tid == 0) st[r] = ms[0] + logf(ss[0]);
}

// ------------------- normalize: fp32 in place (fallback) --------------------
__global__ void k_norm(float* __restrict__ out, const float* __restrict__ st) {
  int r = blockIdx.y;
  int i = blockIdx.x * 256 + threadIdx.x;
  if (i < Vv / 4) {
    float sub = st[r];
    f4* p = (f4*)(out + (size_t)r * Vv) + i;
    f4 v = __builtin_nontemporal_load(p);
    v -= sub;
    __builtin_nontemporal_store(v, p);
  }
}

// ------------------- normalize: bf16 logits -> fp32 out ---------------------
__global__ void k_norm_bf(const unsigned short* __restrict__ lgt,
                          float* __restrict__ out, const float* __restrict__ st) {
  int r = blockIdx.y;
  int i = blockIdx.x * 256 + threadIdx.x;
  if (i < Vv / 8) {
    float sub = st[r];
    us8 v = __builtin_nontemporal_load((const us8*)(lgt + (size_t)r * Vv + i * 8));
    f4 o0, o1;
#pragma unroll
    for (int qk = 0; qk < 4; qk++) {
      union { unsigned u; float f; } cv;
      cv.u = ((unsigned)v[qk]) << 16;
      o0[qk] = cv.f - sub;
    }
#pragma unroll
    for (int qk = 0; qk < 4; qk++) {
      union { unsigned u; float f; } cv;
      cv.u = ((unsigned)v[4 + qk]) << 16;
      o1[qk] = cv.f - sub;
    }
    float* p = out + (size_t)r * Vv + i * 8;
    __builtin_nontemporal_store(o0, (f4*)p);
    __builtin_nontemporal_store(o1, (f4*)(p + 4));
  }
}

// ------------------------- static index outputs -----------------------------
__global__ void k_idx(float* __restrict__ dst) {
  int total = DS.nStart + DS.nEnd + 2 * DS.nS;
  for (int i = threadIdx.x; i < total; i += 256) {
    int v;
    if (i < DS.nStart) v = DS.startIdx[i];
    else if (i < DS.nStart + DS.nEnd) v = DS.endIdx[i - DS.nStart];
    else if (i < DS.nStart + DS.nEnd + DS.nS) v = DS.sOut[i - DS.nStart - DS.nEnd];
    else v = DS.sIn[i - DS.nStart - DS.nEnd - DS.nS];
    dst[i] = (float)v;
  }
}

// ---------------------------------------------------------------------------
extern "C" void kernel_launch(void* const* d_in, const int* in_sizes, int n_in,
                              void* d_out, int out_size, void* d_ws, size_t ws_size,
                              hipStream_t stream) {
  (void)in_sizes; (void)n_in; (void)out_size;
  const float* x    = (const float*)d_in[0];
  const float* Win  = (const float*)d_in[1];
  const float* bin  = (const float*)d_in[2];
  const float* Wg   = (const float*)d_in[3];
  const float* bg   = (const float*)d_in[4];
  const float* Wc   = (const float*)d_in[5];
  const float* bc   = (const float*)d_in[6];
  const float* lng  = (const float*)d_in[7];
  const float* lnb  = (const float*)d_in[8];
  const float* Wl   = (const float*)d_in[9];
  const float* bl   = (const float*)d_in[10];
  const float* Wout = (const float*)d_in[11];
  const float* bout = (const float*)d_in[12];
  float* out = (float*)d_out;

  constexpr int T = HS.T;                          // 351
  constexpr int Mrows = T * Bb;                    // 2808
  constexpr int Mt = ((Mrows + 127) / 128) * 128;  // 2816

  char* ws = (char*)d_ws;
  char* ws0 = ws;
  unsigned short* Wt = (unsigned short*)ws;    ws += (size_t)Vv * Hd * 2;
  unsigned short* Wct = (unsigned short*)ws;   ws += (size_t)2048 * Hd * 2;
  float* hidd = (float*)ws;                    ws += (size_t)Bb * Hd * 4;   // leaf0 only
  unsigned short* hiddb = (unsigned short*)ws; ws += (size_t)Mt * Hd * 2;
  float* gbuf = (float*)ws;                    ws += (size_t)Bb * Hd * 4;
  float* gW = (float*)ws;                      ws += (size_t)Bb * 2048 * 4;
  float* zbuf = (float*)ws;                    ws += (size_t)4 * 256 * 2048 * 4;
  int* bar = (int*)ws;                         ws += 64;
  float2* ptile = (float2*)ws;                 ws += (size_t)Mt * NT * 8;
  float* st = (float*)ws;                      ws += (size_t)Mt * 4;
  unsigned short* lgt = (unsigned short*)ws;   // optional, gated on ws_size
  size_t needBf = (size_t)(ws - ws0) + (size_t)Mt * Vv * 2;
  bool bfp = ws_size >= needBf;

  float* leaves = out + (size_t)Mrows * Vv;
  float* idxdst = leaves + (size_t)Mrows * 2;

  hipMemsetAsync(bar, 0, 8, stream);
  k_wct<<<dim3(2048 / 32, Hd / 32), dim3(32, 8), 0, stream>>>(Wc, Wct);
  k_init<<<dim3(8, 2), dim3(256), 0, stream>>>(x, Wg, bg, Win, bin, gbuf, hidd, hiddb);
  k_gw<<<dim3(16), dim3(256), 0, stream>>>(gbuf, Wc, bc, gW);
  k_leaf0<<<dim3(1), dim3(512), 0, stream>>>(hidd, Wl, bl, leaves);

  k_tree<<<dim3(256), dim3(256), 0, stream>>>(hiddb, Wct, gW, lng, lnb, Wl, bl,
                                              leaves, zbuf, bar, Wout, Wt);

  if (bfp) {
    k_gemm<1><<<dim3(NWG), dim3(256), 0, stream>>>(hiddb, Wt, bout, out, lgt,
                                                   ptile, Mrows);
    k_lse<<<dim3(Mrows), dim3(256), 0, stream>>>(ptile, st);
    k_norm_bf<<<dim3(16, Mrows), dim3(256), 0, stream>>>(lgt, out, st);
  } else {
    k_gemm<0><<<dim3(NWG), dim3(256), 0, stream>>>(hiddb, Wt, bout, out, lgt,
                                                   ptile, Mrows);
    k_lse<<<dim3(Mrows), dim3(256), 0, stream>>>(ptile, st);
    k_norm<<<dim3(32, Mrows), dim3(256), 0, stream>>>(out, st);
  }
  k_idx<<<dim3(1), dim3(256), 0, stream>>>(idxdst);
}